// Round 10
// baseline (246.938 us; speedup 1.0000x reference)
//
#include <hip/hip_runtime.h>
#include <hip/hip_bf16.h>
#include <stdint.h>

#define Bb   8
#define Tt   2048
#define Cdim 1024
#define BT   16384   // Bb*Tt
#define SLAB ((size_t)BT * Cdim)

// wkv geometry: 64 chunks x 32 steps; 32 channels (16 pair-lanes) per block
#define NCb   64
#define LCHb  32

typedef __attribute__((ext_vector_type(4))) float f32x4;
typedef __attribute__((ext_vector_type(8))) short bf16x8;

__device__ inline short f2bs(float f) {
    union { __hip_bfloat16 h; short s; } u;
    u.h = __float2bfloat16(f);
    return u.s;
}
__device__ inline float bs2f(short s) {
    union { short s; __hip_bfloat16 h; } u;
    u.s = s;
    return __bfloat162float(u.h);
}

#define GLOAD_LDS16(g, l) __builtin_amdgcn_global_load_lds( \
    (const __attribute__((address_space(1))) void*)(g),     \
    (__attribute__((address_space(3))) void*)(l), 16, 0, 0)

#define SBAR()      __builtin_amdgcn_s_barrier()

// ---------------------------------------------------------------------------
// prep_all: blocks [0,8192) do xmix lerp; blocks [8192,10240) do W->bf16.
// ---------------------------------------------------------------------------
__global__ __launch_bounds__(256) void prep_all(
    const float* __restrict__ x,
    const float* __restrict__ mk,
    const float* __restrict__ mv,
    const float* __restrict__ mr,
    const float* __restrict__ Wk, const float* __restrict__ Wv,
    const float* __restrict__ Wr, const float* __restrict__ Wo,
    short* __restrict__ xmix,
    short* __restrict__ wbf)
{
    int bid = blockIdx.x;
    if (bid < 8192) {
        int idx = bid * 256 + threadIdx.x;       // [0, BT*Cdim/8)
        int c8  = idx & (Cdim / 8 - 1);
        int m   = idx >> 7;                      // Cdim/8 == 128
        int c0  = c8 << 3;
        int t   = m & (Tt - 1);

        float xs[8], ps[8];
        const float4* xp = (const float4*)(x + (size_t)m * Cdim + c0);
        float4 xa = xp[0], xb = xp[1];
        xs[0]=xa.x; xs[1]=xa.y; xs[2]=xa.z; xs[3]=xa.w;
        xs[4]=xb.x; xs[5]=xb.y; xs[6]=xb.z; xs[7]=xb.w;
        if (t != 0) {
            const float4* pp = (const float4*)(x + (size_t)(m - 1) * Cdim + c0);
            float4 pa = pp[0], pb = pp[1];
            ps[0]=pa.x; ps[1]=pa.y; ps[2]=pa.z; ps[3]=pa.w;
            ps[4]=pb.x; ps[5]=pb.y; ps[6]=pb.z; ps[7]=pb.w;
        } else {
            #pragma unroll
            for (int j = 0; j < 8; ++j) ps[j] = 0.f;
        }

        const float* mixes[3] = {mk, mv, mr};
        #pragma unroll
        for (int z = 0; z < 3; ++z) {
            const float4* mp = (const float4*)(mixes[z] + c0);
            float4 ma = mp[0], mb = mp[1];
            float mm[8];
            mm[0]=ma.x; mm[1]=ma.y; mm[2]=ma.z; mm[3]=ma.w;
            mm[4]=mb.x; mm[5]=mb.y; mm[6]=mb.z; mm[7]=mb.w;
            bf16x8 o;
            #pragma unroll
            for (int j = 0; j < 8; ++j)
                o[j] = f2bs(ps[j] + mm[j] * (xs[j] - ps[j]));
            *(bf16x8*)(xmix + (size_t)z * SLAB + (size_t)m * Cdim + c0) = o;
        }
    } else {
        int idx = (bid - 8192) * 256 + threadIdx.x;  // [0, 4*C*C/8)
        int z   = idx >> 17;                         // C*C/8 == 131072
        int r   = idx & (Cdim * Cdim / 8 - 1);
        const float* src = (z == 0) ? Wk : (z == 1) ? Wv : (z == 2) ? Wr : Wo;
        const float4* sp = (const float4*)(src + (size_t)r * 8);
        float4 a = sp[0], b = sp[1];
        float v[8] = {a.x, a.y, a.z, a.w, b.x, b.y, b.z, b.w};
        bf16x8 o;
        #pragma unroll
        for (int j = 0; j < 8; ++j) o[j] = f2bs(v[j]);
        *(bf16x8*)(wbf + (size_t)z * Cdim * Cdim + (size_t)r * 8) = o;
    }
}

// ---------------------------------------------------------------------------
// gemm256: 256x256 tile, BK=64, 8 waves (2Mx4N), double-buffered LDS,
// XCD-locality mapping (r6), XOR chunk^row&7 swizzle (T2, conflict-free),
// r8 2-phase K-loop (measured 117 us for the fused 3-GEMM dispatch).
// ROUND 10: epilogue reverted to SEPARATE coalesced outputs (the r9
// interleaved-kv store halved sector fill -> WRITE_SIZE 98->171 MB, +24 us).
// FUSED: z=0 -> o0 (k bf16), z=1 -> o1 (v bf16), z=2 -> o2 (sigmoid(r) bf16).
// ---------------------------------------------------------------------------
template<int FUSED>
__global__ __launch_bounds__(512, 2) void gemm256(
    const short* __restrict__ Abase,
    const short* __restrict__ Wbase,
    void* __restrict__ o0, void* __restrict__ o1, void* __restrict__ o2)
{
    __shared__ __align__(16) char lds[131072];

    const int tid  = threadIdx.x;
    const int lane = tid & 63;
    const int wv   = tid >> 6;
    const int wm   = wv >> 2, wn = wv & 3;       // 2 x 4 waves
    const int NT   = Cdim / 64;                  // 16 K-tiles

    // XCD-locality remap (r6): XCD x owns yt in [8x,8x+8), z-major rounds
    int orig = blockIdx.y * (FUSED ? 12 : 4) + blockIdx.x;
    int xcd  = orig & 7;
    int s    = orig >> 3;
    int z, nt, yt;
    if (FUSED) {
        z  = s >> 5;
        int rem = s & 31;
        nt = rem & 3;
        yt = xcd * 8 + (rem >> 2);
    } else {
        z  = 0;
        nt = s & 3;
        yt = xcd * 8 + (s >> 2);
    }

    const short* A  = Abase + (size_t)z * SLAB;
    const short* Bm = Wbase + (size_t)z * Cdim * Cdim;
    const int m0 = yt * 256;
    const int n0 = nt * 256;

    f32x4 acc[8][4] = {};

    // per-lane read offsets (bytes)
    const int lm = lane & 15, lq = lane >> 4, lb7 = lane & 7;
    int ck[2];
    #pragma unroll
    for (int ks = 0; ks < 2; ++ks) ck[ks] = (((ks * 4 + lq) ^ lb7) << 4);
    int aoff[8];
    #pragma unroll
    for (int i = 0; i < 8; ++i) aoff[i] = (i * 16 + lm) * 128;
    int boff[4];
    #pragma unroll
    for (int j = 0; j < 4; ++j) boff[j] = ((wn & 1) * 64 + j * 16 + lm) * 128;
    const int aReg = wm << 14;                   // A-lo / A-hi
    const int bReg = 32768 + ((wn >> 1) << 14);  // B-lo / B-hi

    // stage one half-tile (2 x gload_lds, pre-swizzled global source)
    const int rlo  = tid >> 3;                   // 0..63
    const int clog = (tid & 7) ^ (rlo & 7);
    auto STAGE = [&](int tt, int part) {
        const short* mat = (part < 2) ? A : Bm;
        int rb = ((part < 2) ? m0 : n0) + ((part & 1) << 7);
        const short* g0 = mat + (size_t)(rb + rlo)      * Cdim + (tt << 6) + (clog << 3);
        const short* g1 = mat + (size_t)(rb + 64 + rlo) * Cdim + (tt << 6) + (clog << 3);
        char* l = lds + ((tt & 1) << 16) + (part << 14) + tid * 16;
        GLOAD_LDS16(g0, l);
        GLOAD_LDS16(g1, l + 8192);
    };

    // prologue: t0 all 4 halves + t1 A halves; t0 resident, t1.A in flight
    STAGE(0, 0); STAGE(0, 1); STAGE(0, 2); STAGE(0, 3);
    STAGE(1, 0); STAGE(1, 1);
    asm volatile("s_waitcnt vmcnt(4)" ::: "memory");
    SBAR();

    bf16x8 a0[4][2], a4[4][2], b01[2][2], b23[2][2];

    #pragma unroll 1
    for (int kt = 0; kt < NT; ++kt) {
        const char* base = lds + ((kt & 1) << 16);

        // ---- Ph1: all fragment reads; stage (kt+1).B; MFMA Q00 + Q10 ----
        #pragma unroll
        for (int i = 0; i < 4; ++i)
            #pragma unroll
            for (int ks = 0; ks < 2; ++ks)
                a0[i][ks] = *(const bf16x8*)(base + aReg + aoff[i] + ck[ks]);
        #pragma unroll
        for (int j = 0; j < 2; ++j)
            #pragma unroll
            for (int ks = 0; ks < 2; ++ks)
                b01[j][ks] = *(const bf16x8*)(base + bReg + boff[j] + ck[ks]);
        #pragma unroll
        for (int i = 0; i < 4; ++i)
            #pragma unroll
            for (int ks = 0; ks < 2; ++ks)
                a4[i][ks] = *(const bf16x8*)(base + aReg + aoff[i + 4] + ck[ks]);
        #pragma unroll
        for (int j = 0; j < 2; ++j)
            #pragma unroll
            for (int ks = 0; ks < 2; ++ks)
                b23[j][ks] = *(const bf16x8*)(base + bReg + boff[j + 2] + ck[ks]);
        if (kt + 1 < NT) { STAGE(kt + 1, 2); STAGE(kt + 1, 3); }
        __builtin_amdgcn_s_setprio(1);
        #pragma unroll
        for (int ks = 0; ks < 2; ++ks)
            #pragma unroll
            for (int i = 0; i < 4; ++i)
                #pragma unroll
                for (int j = 0; j < 2; ++j)
                    acc[i][j] = __builtin_amdgcn_mfma_f32_16x16x32_bf16(
                        a0[i][ks], b01[j][ks], acc[i][j], 0, 0, 0);
        #pragma unroll
        for (int ks = 0; ks < 2; ++ks)
            #pragma unroll
            for (int i = 0; i < 4; ++i)
                #pragma unroll
                for (int j = 0; j < 2; ++j)
                    acc[i + 4][j] = __builtin_amdgcn_mfma_f32_16x16x32_bf16(
                        a4[i][ks], b01[j][ks], acc[i + 4][j], 0, 0, 0);
        __builtin_amdgcn_s_setprio(0);
        SBAR();

        // ---- Ph2: stage (kt+2).A; MFMA Q11 + Q01 (held regs); vmcnt ----
        if (kt + 2 < NT) { STAGE(kt + 2, 0); STAGE(kt + 2, 1); }
        __builtin_amdgcn_s_setprio(1);
        #pragma unroll
        for (int ks = 0; ks < 2; ++ks)
            #pragma unroll
            for (int i = 0; i < 4; ++i)
                #pragma unroll
                for (int j = 0; j < 2; ++j)
                    acc[i + 4][j + 2] = __builtin_amdgcn_mfma_f32_16x16x32_bf16(
                        a4[i][ks], b23[j][ks], acc[i + 4][j + 2], 0, 0, 0);
        #pragma unroll
        for (int ks = 0; ks < 2; ++ks)
            #pragma unroll
            for (int i = 0; i < 4; ++i)
                #pragma unroll
                for (int j = 0; j < 2; ++j)
                    acc[i][j + 2] = __builtin_amdgcn_mfma_f32_16x16x32_bf16(
                        a0[i][ks], b23[j][ks], acc[i][j + 2], 0, 0, 0);
        __builtin_amdgcn_s_setprio(0);
        if      (kt + 2 < NT) { asm volatile("s_waitcnt vmcnt(4)" ::: "memory"); }
        else if (kt + 1 < NT) { asm volatile("s_waitcnt vmcnt(0)" ::: "memory"); }
        SBAR();
    }

    // epilogue: C/D layout col = lane&15, row = (lane>>4)*4 + r  [m89]
    int col0 = n0 + wn * 64 + lm;
    int row0 = m0 + wm * 128 + (lq << 2);
    #pragma unroll
    for (int i = 0; i < 8; ++i) {
        #pragma unroll
        for (int j = 0; j < 4; ++j) {
            #pragma unroll
            for (int r = 0; r < 4; ++r) {
                int row = row0 + i * 16 + r;
                int cc  = col0 + j * 16;
                float vvv = acc[i][j][r];
                if (FUSED) {
                    short* outb = (short*)((z == 0) ? o0 : (z == 1) ? o1 : o2);
                    if (z == 2) vvv = 1.f / (1.f + __expf(-vvv));
                    outb[(size_t)row * Cdim + cc] = f2bs(vvv);
                } else {
                    ((float*)o0)[(size_t)row * Cdim + cc] = vvv;
                }
            }
        }
    }
}

// ---------------------------------------------------------------------------
// wkv_chunked: chunked-parallel stable WKV scan, 2 channels per thread.
// Each thread owns channels (c0, c0+1): k/v/r pair loads are single dwords,
// two independent recurrence chains give ILP-2 on the serial dependent chain.
// Block: 64 chunks (LCH=32) x 16 pair-lanes = 1024 thr, 32 channels/block;
// grid = Bb * Cdim/32 = 256. r is PRE-SIGMOIDED bf16.
// ---------------------------------------------------------------------------
__global__ __launch_bounds__(1024) void wkv_chunked(
    const short* __restrict__ kb, const short* __restrict__ vb,
    const short* __restrict__ srb,
    const float* __restrict__ w, const float* __restrict__ u,
    short* __restrict__ rwkv)
{
    __shared__ float sp[NCb][32], sq[NCb][32], so[NCb][32];

    int tid = threadIdx.x;
    int pl  = tid & 15;                 // pair-lane
    int ch  = tid >> 4;                 // chunk 0..63
    int b   = blockIdx.x >> 5;
    int cg  = blockIdx.x & 31;
    int c0  = cg * 32 + pl * 2;         // channels c0, c0+1

    float w0 = -__expf(w[c0]),     w1 = -__expf(w[c0 + 1]);
    float u0 = u[c0],              u1 = u[c0 + 1];
    size_t coff = (size_t)b * Tt * Cdim + (size_t)(ch * LCHb) * Cdim + c0;

    // ---- phase 1: local chunk summaries (two chains, ILP) ----
    float p0 = 0.f, q0 = 0.f, o0 = -1e30f;
    float p1 = 0.f, q1 = 0.f, o1 = -1e30f;
    #pragma unroll 8
    for (int t = 0; t < LCHb; ++t) {
        size_t off = coff + (size_t)t * Cdim;
        int kk = *(const int*)(kb + off);
        int vv = *(const int*)(vb + off);
        float k0 = bs2f((short)kk), k1 = bs2f((short)((unsigned)kk >> 16));
        float v0 = bs2f((short)vv), v1 = bs2f((short)((unsigned)vv >> 16));
        float wo0 = w0 + o0,            wo1 = w1 + o1;
        float no0 = fmaxf(wo0, k0),     no1 = fmaxf(wo1, k1);
        float A0  = __expf(wo0 - no0),  A1  = __expf(wo1 - no1);
        float B0  = __expf(k0 - no0),   B1  = __expf(k1 - no1);
        p0 = A0 * p0 + B0 * v0;         p1 = A1 * p1 + B1 * v1;
        q0 = A0 * q0 + B0;              q1 = A1 * q1 + B1;
        o0 = no0;                       o1 = no1;
    }
    sp[ch][pl * 2] = p0; sq[ch][pl * 2] = q0; so[ch][pl * 2] = o0;
    sp[ch][pl * 2 + 1] = p1; sq[ch][pl * 2 + 1] = q1; so[ch][pl * 2 + 1] = o1;
    __syncthreads();

    // ---- phase 2: exclusive combine-scan (16 threads x 2 channels, ILP) ----
    if (tid < 16) {
        int lcA = tid * 2, lcB = tid * 2 + 1;
        float LdA = -__expf(w[cg * 32 + lcA]) * (float)LCHb;
        float LdB = -__expf(w[cg * 32 + lcB]) * (float)LCHb;
        float cpA = 0.f, cqA = 0.f, coA = -1e30f;
        float cpB = 0.f, cqB = 0.f, coB = -1e30f;
        for (int j = 0; j < NCb; ++j) {
            float lpA = sp[j][lcA], lqA = sq[j][lcA], loA = so[j][lcA];
            float lpB = sp[j][lcB], lqB = sq[j][lcB], loB = so[j][lcB];
            sp[j][lcA] = cpA; sq[j][lcA] = cqA; so[j][lcA] = coA;
            sp[j][lcB] = cpB; sq[j][lcB] = cqB; so[j][lcB] = coB;
            float odA = coA + LdA,          odB = coB + LdB;
            float noA = fmaxf(odA, loA),    noB = fmaxf(odB, loB);
            float AA  = __expf(odA - noA),  AB  = __expf(odB - noB);
            float BA  = __expf(loA - noA),  BB  = __expf(loB - noB);
            cpA = AA * cpA + BA * lpA;      cpB = AB * cpB + BB * lpB;
            cqA = AA * cqA + BA * lqA;      cqB = AB * cqB + BB * lqB;
            coA = noA;                      coB = noB;
        }
    }
    __syncthreads();

    // ---- phase 3: outputs from incoming state (two chains, ILP) ----
    p0 = sp[ch][pl * 2]; q0 = sq[ch][pl * 2]; o0 = so[ch][pl * 2];
    p1 = sp[ch][pl * 2 + 1]; q1 = sq[ch][pl * 2 + 1]; o1 = so[ch][pl * 2 + 1];
    #pragma unroll 8
    for (int t = 0; t < LCHb; ++t) {
        size_t off = coff + (size_t)t * Cdim;
        int kk = *(const int*)(kb + off);
        int vv = *(const int*)(vb + off);
        int rr = *(const int*)(srb + off);
        float k0 = bs2f((short)kk), k1 = bs2f((short)((unsigned)kk >> 16));
        float v0 = bs2f((short)vv), v1 = bs2f((short)((unsigned)vv >> 16));
        float s0 = bs2f((short)rr), s1 = bs2f((short)((unsigned)rr >> 16));

        float uk0 = u0 + k0,            uk1 = u1 + k1;
        float no0 = fmaxf(o0, uk0),     no1 = fmaxf(o1, uk1);
        float Aa0 = __expf(o0 - no0),   Aa1 = __expf(o1 - no1);
        float Bc0 = __expf(uk0 - no0),  Bc1 = __expf(uk1 - no1);
        float out0 = (Aa0 * p0 + Bc0 * v0) / (Aa0 * q0 + Bc0);
        float out1 = (Aa1 * p1 + Bc1 * v1) / (Aa1 * q1 + Bc1);

        float wo0 = w0 + o0,            wo1 = w1 + o1;
        float n20 = fmaxf(wo0, k0),     n21 = fmaxf(wo1, k1);
        float A20 = __expf(wo0 - n20),  A21 = __expf(wo1 - n21);
        float B20 = __expf(k0 - n20),   B21 = __expf(k1 - n21);
        p0 = A20 * p0 + B20 * v0;       p1 = A21 * p1 + B21 * v1;
        q0 = A20 * q0 + B20;            q1 = A21 * q1 + B21;
        o0 = n20;                       o1 = n21;

        unsigned lo = (unsigned short)f2bs(s0 * out0);
        unsigned hi = (unsigned short)f2bs(s1 * out1);
        *(unsigned*)(rwkv + off) = lo | (hi << 16);
    }
}

// ---------------------------------------------------------------------------
extern "C" void kernel_launch(void* const* d_in, const int* in_sizes, int n_in,
                              void* d_out, int out_size, void* d_ws, size_t ws_size,
                              hipStream_t stream)
{
    const float* x    = (const float*)d_in[0];
    const float* w    = (const float*)d_in[1];
    const float* u    = (const float*)d_in[2];
    const float* mixk = (const float*)d_in[3];
    const float* mixv = (const float*)d_in[4];
    const float* mixr = (const float*)d_in[5];
    const float* Wk   = (const float*)d_in[6];
    const float* Wv   = (const float*)d_in[7];
    const float* Wr   = (const float*)d_in[8];
    const float* Wo   = (const float*)d_in[9];

    char* ws = (char*)d_ws;
    short* xmix = (short*)ws;                        // 3 slabs bf16 = 96 MiB
    short* wbf  = (short*)(ws + 3 * SLAB * 2);       // 4*C*C bf16 = 8 MiB
    short* rbuf = (short*)(ws + 3 * SLAB * 2 + (size_t)4 * Cdim * Cdim * 2); // 32 MiB
    short* rwkv = (short*)ws;                        // reuses dead xmix slab 0
    short* kbuf = (short*)d_out;                     // k,v bf16 live in d_out
    short* vbuf = kbuf + SLAB;                       // exactly fills 64 MiB

    // single prep dispatch: 8192 xmix blocks + 2048 W blocks
    prep_all<<<8192 + 2048, 256, 0, stream>>>(x, mixk, mixv, mixr,
                                              Wk, Wv, Wr, Wo, xmix, wbf);

    // fused k/v/r GEMM: grid (12,64) = 768 blocks
    dim3 gf(12, BT / 256);
    gemm256<1><<<gf, 512, 0, stream>>>(xmix, wbf, kbuf, vbuf, rbuf);

    wkv_chunked<<<Bb * (Cdim / 32), 1024, 0, stream>>>(kbuf, vbuf, rbuf, w, u, rwkv);

    // output GEMM: grid (4,64) = 256 blocks, f32 out
    dim3 go(Cdim / 256, BT / 256);
    gemm256<0><<<go, 512, 0, stream>>>(rwkv, wbf + 3 * (size_t)Cdim * Cdim,
                                       (float*)d_out, nullptr, nullptr);
}

// Round 11
// 238.918 us; speedup vs baseline: 1.0336x; 1.0336x over previous
//
#include <hip/hip_runtime.h>
#include <hip/hip_bf16.h>
#include <stdint.h>

#define Bb   8
#define Tt   2048
#define Cdim 1024
#define BT   16384   // Bb*Tt
#define SLAB ((size_t)BT * Cdim)

// wkv geometry: 32 chunks x 64 steps; 64 channels (32 pair-lanes) per block
#define NCb   32
#define LCHb  64

typedef __attribute__((ext_vector_type(4))) float f32x4;
typedef __attribute__((ext_vector_type(8))) short bf16x8;

__device__ inline short f2bs(float f) {
    union { __hip_bfloat16 h; short s; } u;
    u.h = __float2bfloat16(f);
    return u.s;
}
__device__ inline float bs2f(short s) {
    union { short s; __hip_bfloat16 h; } u;
    u.s = s;
    return __bfloat162float(u.h);
}

#define GLOAD_LDS16(g, l) __builtin_amdgcn_global_load_lds( \
    (const __attribute__((address_space(1))) void*)(g),     \
    (__attribute__((address_space(3))) void*)(l), 16, 0, 0)

#define SBAR()      __builtin_amdgcn_s_barrier()

// ---------------------------------------------------------------------------
// prep_all: blocks [0,8192) do xmix lerp; blocks [8192,10240) do W->bf16.
// ---------------------------------------------------------------------------
__global__ __launch_bounds__(256) void prep_all(
    const float* __restrict__ x,
    const float* __restrict__ mk,
    const float* __restrict__ mv,
    const float* __restrict__ mr,
    const float* __restrict__ Wk, const float* __restrict__ Wv,
    const float* __restrict__ Wr, const float* __restrict__ Wo,
    short* __restrict__ xmix,
    short* __restrict__ wbf)
{
    int bid = blockIdx.x;
    if (bid < 8192) {
        int idx = bid * 256 + threadIdx.x;       // [0, BT*Cdim/8)
        int c8  = idx & (Cdim / 8 - 1);
        int m   = idx >> 7;                      // Cdim/8 == 128
        int c0  = c8 << 3;
        int t   = m & (Tt - 1);

        float xs[8], ps[8];
        const float4* xp = (const float4*)(x + (size_t)m * Cdim + c0);
        float4 xa = xp[0], xb = xp[1];
        xs[0]=xa.x; xs[1]=xa.y; xs[2]=xa.z; xs[3]=xa.w;
        xs[4]=xb.x; xs[5]=xb.y; xs[6]=xb.z; xs[7]=xb.w;
        if (t != 0) {
            const float4* pp = (const float4*)(x + (size_t)(m - 1) * Cdim + c0);
            float4 pa = pp[0], pb = pp[1];
            ps[0]=pa.x; ps[1]=pa.y; ps[2]=pa.z; ps[3]=pa.w;
            ps[4]=pb.x; ps[5]=pb.y; ps[6]=pb.z; ps[7]=pb.w;
        } else {
            #pragma unroll
            for (int j = 0; j < 8; ++j) ps[j] = 0.f;
        }

        const float* mixes[3] = {mk, mv, mr};
        #pragma unroll
        for (int z = 0; z < 3; ++z) {
            const float4* mp = (const float4*)(mixes[z] + c0);
            float4 ma = mp[0], mb = mp[1];
            float mm[8];
            mm[0]=ma.x; mm[1]=ma.y; mm[2]=ma.z; mm[3]=ma.w;
            mm[4]=mb.x; mm[5]=mb.y; mm[6]=mb.z; mm[7]=mb.w;
            bf16x8 o;
            #pragma unroll
            for (int j = 0; j < 8; ++j)
                o[j] = f2bs(ps[j] + mm[j] * (xs[j] - ps[j]));
            *(bf16x8*)(xmix + (size_t)z * SLAB + (size_t)m * Cdim + c0) = o;
        }
    } else {
        int idx = (bid - 8192) * 256 + threadIdx.x;  // [0, 4*C*C/8)
        int z   = idx >> 17;                         // C*C/8 == 131072
        int r   = idx & (Cdim * Cdim / 8 - 1);
        const float* src = (z == 0) ? Wk : (z == 1) ? Wv : (z == 2) ? Wr : Wo;
        const float4* sp = (const float4*)(src + (size_t)r * 8);
        float4 a = sp[0], b = sp[1];
        float v[8] = {a.x, a.y, a.z, a.w, b.x, b.y, b.z, b.w};
        bf16x8 o;
        #pragma unroll
        for (int j = 0; j < 8; ++j) o[j] = f2bs(v[j]);
        *(bf16x8*)(wbf + (size_t)z * Cdim * Cdim + (size_t)r * 8) = o;
    }
}

// ---------------------------------------------------------------------------
// gemm256: 256x256 tile, BK=64, 8 waves (2Mx4N), double-buffered LDS,
// XCD-locality mapping (r6), XOR chunk^row&7 swizzle (T2, conflict-free),
// r8 2-phase K-loop, separate coalesced outputs (r10: fused = ~116 us).
// FUSED: z=0 -> o0 (k bf16), z=1 -> o1 (v bf16), z=2 -> o2 (sigmoid(r) bf16).
// ---------------------------------------------------------------------------
template<int FUSED>
__global__ __launch_bounds__(512, 2) void gemm256(
    const short* __restrict__ Abase,
    const short* __restrict__ Wbase,
    void* __restrict__ o0, void* __restrict__ o1, void* __restrict__ o2)
{
    __shared__ __align__(16) char lds[131072];

    const int tid  = threadIdx.x;
    const int lane = tid & 63;
    const int wv   = tid >> 6;
    const int wm   = wv >> 2, wn = wv & 3;       // 2 x 4 waves
    const int NT   = Cdim / 64;                  // 16 K-tiles

    // XCD-locality remap (r6): XCD x owns yt in [8x,8x+8), z-major rounds
    int orig = blockIdx.y * (FUSED ? 12 : 4) + blockIdx.x;
    int xcd  = orig & 7;
    int s    = orig >> 3;
    int z, nt, yt;
    if (FUSED) {
        z  = s >> 5;
        int rem = s & 31;
        nt = rem & 3;
        yt = xcd * 8 + (rem >> 2);
    } else {
        z  = 0;
        nt = s & 3;
        yt = xcd * 8 + (s >> 2);
    }

    const short* A  = Abase + (size_t)z * SLAB;
    const short* Bm = Wbase + (size_t)z * Cdim * Cdim;
    const int m0 = yt * 256;
    const int n0 = nt * 256;

    f32x4 acc[8][4] = {};

    // per-lane read offsets (bytes)
    const int lm = lane & 15, lq = lane >> 4, lb7 = lane & 7;
    int ck[2];
    #pragma unroll
    for (int ks = 0; ks < 2; ++ks) ck[ks] = (((ks * 4 + lq) ^ lb7) << 4);
    int aoff[8];
    #pragma unroll
    for (int i = 0; i < 8; ++i) aoff[i] = (i * 16 + lm) * 128;
    int boff[4];
    #pragma unroll
    for (int j = 0; j < 4; ++j) boff[j] = ((wn & 1) * 64 + j * 16 + lm) * 128;
    const int aReg = wm << 14;                   // A-lo / A-hi
    const int bReg = 32768 + ((wn >> 1) << 14);  // B-lo / B-hi

    // stage one half-tile (2 x gload_lds, pre-swizzled global source)
    const int rlo  = tid >> 3;                   // 0..63
    const int clog = (tid & 7) ^ (rlo & 7);
    auto STAGE = [&](int tt, int part) {
        const short* mat = (part < 2) ? A : Bm;
        int rb = ((part < 2) ? m0 : n0) + ((part & 1) << 7);
        const short* g0 = mat + (size_t)(rb + rlo)      * Cdim + (tt << 6) + (clog << 3);
        const short* g1 = mat + (size_t)(rb + 64 + rlo) * Cdim + (tt << 6) + (clog << 3);
        char* l = lds + ((tt & 1) << 16) + (part << 14) + tid * 16;
        GLOAD_LDS16(g0, l);
        GLOAD_LDS16(g1, l + 8192);
    };

    // prologue: t0 all 4 halves + t1 A halves; t0 resident, t1.A in flight
    STAGE(0, 0); STAGE(0, 1); STAGE(0, 2); STAGE(0, 3);
    STAGE(1, 0); STAGE(1, 1);
    asm volatile("s_waitcnt vmcnt(4)" ::: "memory");
    SBAR();

    bf16x8 a0[4][2], a4[4][2], b01[2][2], b23[2][2];

    #pragma unroll 1
    for (int kt = 0; kt < NT; ++kt) {
        const char* base = lds + ((kt & 1) << 16);

        // ---- Ph1: all fragment reads; stage (kt+1).B; MFMA Q00 + Q10 ----
        #pragma unroll
        for (int i = 0; i < 4; ++i)
            #pragma unroll
            for (int ks = 0; ks < 2; ++ks)
                a0[i][ks] = *(const bf16x8*)(base + aReg + aoff[i] + ck[ks]);
        #pragma unroll
        for (int j = 0; j < 2; ++j)
            #pragma unroll
            for (int ks = 0; ks < 2; ++ks)
                b01[j][ks] = *(const bf16x8*)(base + bReg + boff[j] + ck[ks]);
        #pragma unroll
        for (int i = 0; i < 4; ++i)
            #pragma unroll
            for (int ks = 0; ks < 2; ++ks)
                a4[i][ks] = *(const bf16x8*)(base + aReg + aoff[i + 4] + ck[ks]);
        #pragma unroll
        for (int j = 0; j < 2; ++j)
            #pragma unroll
            for (int ks = 0; ks < 2; ++ks)
                b23[j][ks] = *(const bf16x8*)(base + bReg + boff[j + 2] + ck[ks]);
        if (kt + 1 < NT) { STAGE(kt + 1, 2); STAGE(kt + 1, 3); }
        __builtin_amdgcn_s_setprio(1);
        #pragma unroll
        for (int ks = 0; ks < 2; ++ks)
            #pragma unroll
            for (int i = 0; i < 4; ++i)
                #pragma unroll
                for (int j = 0; j < 2; ++j)
                    acc[i][j] = __builtin_amdgcn_mfma_f32_16x16x32_bf16(
                        a0[i][ks], b01[j][ks], acc[i][j], 0, 0, 0);
        #pragma unroll
        for (int ks = 0; ks < 2; ++ks)
            #pragma unroll
            for (int i = 0; i < 4; ++i)
                #pragma unroll
                for (int j = 0; j < 2; ++j)
                    acc[i + 4][j] = __builtin_amdgcn_mfma_f32_16x16x32_bf16(
                        a4[i][ks], b01[j][ks], acc[i + 4][j], 0, 0, 0);
        __builtin_amdgcn_s_setprio(0);
        SBAR();

        // ---- Ph2: stage (kt+2).A; MFMA Q11 + Q01 (held regs); vmcnt ----
        if (kt + 2 < NT) { STAGE(kt + 2, 0); STAGE(kt + 2, 1); }
        __builtin_amdgcn_s_setprio(1);
        #pragma unroll
        for (int ks = 0; ks < 2; ++ks)
            #pragma unroll
            for (int i = 0; i < 4; ++i)
                #pragma unroll
                for (int j = 0; j < 2; ++j)
                    acc[i + 4][j + 2] = __builtin_amdgcn_mfma_f32_16x16x32_bf16(
                        a4[i][ks], b23[j][ks], acc[i + 4][j + 2], 0, 0, 0);
        #pragma unroll
        for (int ks = 0; ks < 2; ++ks)
            #pragma unroll
            for (int i = 0; i < 4; ++i)
                #pragma unroll
                for (int j = 0; j < 2; ++j)
                    acc[i][j + 2] = __builtin_amdgcn_mfma_f32_16x16x32_bf16(
                        a0[i][ks], b23[j][ks], acc[i][j + 2], 0, 0, 0);
        __builtin_amdgcn_s_setprio(0);
        if      (kt + 2 < NT) { asm volatile("s_waitcnt vmcnt(4)" ::: "memory"); }
        else if (kt + 1 < NT) { asm volatile("s_waitcnt vmcnt(0)" ::: "memory"); }
        SBAR();
    }

    // epilogue: C/D layout col = lane&15, row = (lane>>4)*4 + r  [m89]
    int col0 = n0 + wn * 64 + lm;
    int row0 = m0 + wm * 128 + (lq << 2);
    #pragma unroll
    for (int i = 0; i < 8; ++i) {
        #pragma unroll
        for (int j = 0; j < 4; ++j) {
            #pragma unroll
            for (int r = 0; r < 4; ++r) {
                int row = row0 + i * 16 + r;
                int cc  = col0 + j * 16;
                float vvv = acc[i][j][r];
                if (FUSED) {
                    short* outb = (short*)((z == 0) ? o0 : (z == 1) ? o1 : o2);
                    if (z == 2) vvv = 1.f / (1.f + __expf(-vvv));
                    outb[(size_t)row * Cdim + cc] = f2bs(vvv);
                } else {
                    ((float*)o0)[(size_t)row * Cdim + cc] = vvv;
                }
            }
        }
    }
}

// ---------------------------------------------------------------------------
// wkv_chunked: chunked-parallel stable WKV scan, 2 channels per thread with
// r9's wave geometry: 32 pair-lanes (128 B contiguous runs, 2 segments/instr)
// x 32 chunks (LCH=64). Block = 1024 thr = 64 channels; grid = Bb*Cdim/64.
// Per channel per step: phase1 = 1 dword load, phase3 = 1.5 — below r9's
// packed-kv cost, with fully-dense GEMM stores kept. r PRE-SIGMOIDED bf16.
// ---------------------------------------------------------------------------
__global__ __launch_bounds__(1024) void wkv_chunked(
    const short* __restrict__ kb, const short* __restrict__ vb,
    const short* __restrict__ srb,
    const float* __restrict__ w, const float* __restrict__ u,
    short* __restrict__ rwkv)
{
    __shared__ float sp[NCb][64], sq[NCb][64], so[NCb][64];

    int tid = threadIdx.x;
    int pl  = tid & 31;                 // pair-lane 0..31
    int ch  = tid >> 5;                 // chunk 0..31
    int b   = blockIdx.x >> 4;          // grid = Bb * (Cdim/64) = 8*16
    int cg  = blockIdx.x & 15;
    int c0  = cg * 64 + pl * 2;         // channels c0, c0+1

    float w0 = -__expf(w[c0]),     w1 = -__expf(w[c0 + 1]);
    float u0 = u[c0],              u1 = u[c0 + 1];
    size_t coff = (size_t)b * Tt * Cdim + (size_t)(ch * LCHb) * Cdim + c0;

    // ---- phase 1: local chunk summaries (two chains, ILP) ----
    float p0 = 0.f, q0 = 0.f, o0 = -1e30f;
    float p1 = 0.f, q1 = 0.f, o1 = -1e30f;
    #pragma unroll 4
    for (int t = 0; t < LCHb; ++t) {
        size_t off = coff + (size_t)t * Cdim;
        int kk = *(const int*)(kb + off);
        int vv = *(const int*)(vb + off);
        float k0 = bs2f((short)kk), k1 = bs2f((short)((unsigned)kk >> 16));
        float v0 = bs2f((short)vv), v1 = bs2f((short)((unsigned)vv >> 16));
        float wo0 = w0 + o0,            wo1 = w1 + o1;
        float no0 = fmaxf(wo0, k0),     no1 = fmaxf(wo1, k1);
        float A0  = __expf(wo0 - no0),  A1  = __expf(wo1 - no1);
        float B0  = __expf(k0 - no0),   B1  = __expf(k1 - no1);
        p0 = A0 * p0 + B0 * v0;         p1 = A1 * p1 + B1 * v1;
        q0 = A0 * q0 + B0;              q1 = A1 * q1 + B1;
        o0 = no0;                       o1 = no1;
    }
    sp[ch][pl * 2] = p0; sq[ch][pl * 2] = q0; so[ch][pl * 2] = o0;
    sp[ch][pl * 2 + 1] = p1; sq[ch][pl * 2 + 1] = q1; so[ch][pl * 2 + 1] = o1;
    __syncthreads();

    // ---- phase 2: exclusive combine-scan (32 threads x 2 channels, ILP) ----
    if (tid < 32) {
        int lcA = tid * 2, lcB = tid * 2 + 1;
        float LdA = -__expf(w[cg * 64 + lcA]) * (float)LCHb;
        float LdB = -__expf(w[cg * 64 + lcB]) * (float)LCHb;
        float cpA = 0.f, cqA = 0.f, coA = -1e30f;
        float cpB = 0.f, cqB = 0.f, coB = -1e30f;
        for (int j = 0; j < NCb; ++j) {
            float lpA = sp[j][lcA], lqA = sq[j][lcA], loA = so[j][lcA];
            float lpB = sp[j][lcB], lqB = sq[j][lcB], loB = so[j][lcB];
            sp[j][lcA] = cpA; sq[j][lcA] = cqA; so[j][lcA] = coA;
            sp[j][lcB] = cpB; sq[j][lcB] = cqB; so[j][lcB] = coB;
            float odA = coA + LdA,          odB = coB + LdB;
            float noA = fmaxf(odA, loA),    noB = fmaxf(odB, loB);
            float AA  = __expf(odA - noA),  AB  = __expf(odB - noB);
            float BA  = __expf(loA - noA),  BB  = __expf(loB - noB);
            cpA = AA * cpA + BA * lpA;      cpB = AB * cpB + BB * lpB;
            cqA = AA * cqA + BA * lqA;      cqB = AB * cqB + BB * lqB;
            coA = noA;                      coB = noB;
        }
    }
    __syncthreads();

    // ---- phase 3: outputs from incoming state (two chains, ILP) ----
    p0 = sp[ch][pl * 2]; q0 = sq[ch][pl * 2]; o0 = so[ch][pl * 2];
    p1 = sp[ch][pl * 2 + 1]; q1 = sq[ch][pl * 2 + 1]; o1 = so[ch][pl * 2 + 1];
    #pragma unroll 4
    for (int t = 0; t < LCHb; ++t) {
        size_t off = coff + (size_t)t * Cdim;
        int kk = *(const int*)(kb + off);
        int vv = *(const int*)(vb + off);
        int rr = *(const int*)(srb + off);
        float k0 = bs2f((short)kk), k1 = bs2f((short)((unsigned)kk >> 16));
        float v0 = bs2f((short)vv), v1 = bs2f((short)((unsigned)vv >> 16));
        float s0 = bs2f((short)rr), s1 = bs2f((short)((unsigned)rr >> 16));

        float uk0 = u0 + k0,            uk1 = u1 + k1;
        float no0 = fmaxf(o0, uk0),     no1 = fmaxf(o1, uk1);
        float Aa0 = __expf(o0 - no0),   Aa1 = __expf(o1 - no1);
        float Bc0 = __expf(uk0 - no0),  Bc1 = __expf(uk1 - no1);
        float out0 = (Aa0 * p0 + Bc0 * v0) / (Aa0 * q0 + Bc0);
        float out1 = (Aa1 * p1 + Bc1 * v1) / (Aa1 * q1 + Bc1);

        float wo0 = w0 + o0,            wo1 = w1 + o1;
        float n20 = fmaxf(wo0, k0),     n21 = fmaxf(wo1, k1);
        float A20 = __expf(wo0 - n20),  A21 = __expf(wo1 - n21);
        float B20 = __expf(k0 - n20),   B21 = __expf(k1 - n21);
        p0 = A20 * p0 + B20 * v0;       p1 = A21 * p1 + B21 * v1;
        q0 = A20 * q0 + B20;            q1 = A21 * q1 + B21;
        o0 = n20;                       o1 = n21;

        unsigned lo = (unsigned short)f2bs(s0 * out0);
        unsigned hi = (unsigned short)f2bs(s1 * out1);
        *(unsigned*)(rwkv + off) = lo | (hi << 16);
    }
}

// ---------------------------------------------------------------------------
extern "C" void kernel_launch(void* const* d_in, const int* in_sizes, int n_in,
                              void* d_out, int out_size, void* d_ws, size_t ws_size,
                              hipStream_t stream)
{
    const float* x    = (const float*)d_in[0];
    const float* w    = (const float*)d_in[1];
    const float* u    = (const float*)d_in[2];
    const float* mixk = (const float*)d_in[3];
    const float* mixv = (const float*)d_in[4];
    const float* mixr = (const float*)d_in[5];
    const float* Wk   = (const float*)d_in[6];
    const float* Wv   = (const float*)d_in[7];
    const float* Wr   = (const float*)d_in[8];
    const float* Wo   = (const float*)d_in[9];

    char* ws = (char*)d_ws;
    short* xmix = (short*)ws;                        // 3 slabs bf16 = 96 MiB
    short* wbf  = (short*)(ws + 3 * SLAB * 2);       // 4*C*C bf16 = 8 MiB
    short* rbuf = (short*)(ws + 3 * SLAB * 2 + (size_t)4 * Cdim * Cdim * 2); // 32 MiB
    short* rwkv = (short*)ws;                        // reuses dead xmix slab 0
    short* kbuf = (short*)d_out;                     // k,v bf16 live in d_out
    short* vbuf = kbuf + SLAB;                       // exactly fills 64 MiB

    // single prep dispatch: 8192 xmix blocks + 2048 W blocks
    prep_all<<<8192 + 2048, 256, 0, stream>>>(x, mixk, mixv, mixr,
                                              Wk, Wv, Wr, Wo, xmix, wbf);

    // fused k/v/r GEMM: grid (12,64) = 768 blocks
    dim3 gf(12, BT / 256);
    gemm256<1><<<gf, 512, 0, stream>>>(xmix, wbf, kbuf, vbuf, rbuf);

    wkv_chunked<<<Bb * (Cdim / 64), 1024, 0, stream>>>(kbuf, vbuf, rbuf, w, u, rwkv);

    // output GEMM: grid (4,64) = 256 blocks, f32 out
    dim3 go(Cdim / 256, BT / 256);
    gemm256<0><<<go, 512, 0, stream>>>(rwkv, wbf + 3 * (size_t)Cdim * Cdim,
                                       (float*)d_out, nullptr, nullptr);
}

// Round 12
// 230.201 us; speedup vs baseline: 1.0727x; 1.0379x over previous
//
#include <hip/hip_runtime.h>
#include <hip/hip_bf16.h>
#include <stdint.h>

#define Bb   8
#define Tt   2048
#define Cdim 1024
#define BT   16384   // Bb*Tt
#define SLAB ((size_t)BT * Cdim)

// chunked WKV scan geometry (r9-proven: ~27 us with packed kv)
#define NC   32            // chunks per chain
#define LCH  64            // Tt / NC
#define CSUB 32            // channels per block

typedef __attribute__((ext_vector_type(4))) float f32x4;
typedef __attribute__((ext_vector_type(8))) short bf16x8;

__device__ inline short f2bs(float f) {
    union { __hip_bfloat16 h; short s; } u;
    u.h = __float2bfloat16(f);
    return u.s;
}
__device__ inline float bs2f(short s) {
    union { short s; __hip_bfloat16 h; } u;
    u.s = s;
    return __bfloat162float(u.h);
}

#define GLOAD_LDS16(g, l) __builtin_amdgcn_global_load_lds( \
    (const __attribute__((address_space(1))) void*)(g),     \
    (__attribute__((address_space(3))) void*)(l), 16, 0, 0)

#define SBAR()      __builtin_amdgcn_s_barrier()

// ---------------------------------------------------------------------------
// prep_all: blocks [0,8192) do xmix lerp; blocks [8192,10240) do W->bf16.
// ---------------------------------------------------------------------------
__global__ __launch_bounds__(256) void prep_all(
    const float* __restrict__ x,
    const float* __restrict__ mk,
    const float* __restrict__ mv,
    const float* __restrict__ mr,
    const float* __restrict__ Wk, const float* __restrict__ Wv,
    const float* __restrict__ Wr, const float* __restrict__ Wo,
    short* __restrict__ xmix,
    short* __restrict__ wbf)
{
    int bid = blockIdx.x;
    if (bid < 8192) {
        int idx = bid * 256 + threadIdx.x;       // [0, BT*Cdim/8)
        int c8  = idx & (Cdim / 8 - 1);
        int m   = idx >> 7;                      // Cdim/8 == 128
        int c0  = c8 << 3;
        int t   = m & (Tt - 1);

        float xs[8], ps[8];
        const float4* xp = (const float4*)(x + (size_t)m * Cdim + c0);
        float4 xa = xp[0], xb = xp[1];
        xs[0]=xa.x; xs[1]=xa.y; xs[2]=xa.z; xs[3]=xa.w;
        xs[4]=xb.x; xs[5]=xb.y; xs[6]=xb.z; xs[7]=xb.w;
        if (t != 0) {
            const float4* pp = (const float4*)(x + (size_t)(m - 1) * Cdim + c0);
            float4 pa = pp[0], pb = pp[1];
            ps[0]=pa.x; ps[1]=pa.y; ps[2]=pa.z; ps[3]=pa.w;
            ps[4]=pb.x; ps[5]=pb.y; ps[6]=pb.z; ps[7]=pb.w;
        } else {
            #pragma unroll
            for (int j = 0; j < 8; ++j) ps[j] = 0.f;
        }

        const float* mixes[3] = {mk, mv, mr};
        #pragma unroll
        for (int z = 0; z < 3; ++z) {
            const float4* mp = (const float4*)(mixes[z] + c0);
            float4 ma = mp[0], mb = mp[1];
            float mm[8];
            mm[0]=ma.x; mm[1]=ma.y; mm[2]=ma.z; mm[3]=ma.w;
            mm[4]=mb.x; mm[5]=mb.y; mm[6]=mb.z; mm[7]=mb.w;
            bf16x8 o;
            #pragma unroll
            for (int j = 0; j < 8; ++j)
                o[j] = f2bs(ps[j] + mm[j] * (xs[j] - ps[j]));
            *(bf16x8*)(xmix + (size_t)z * SLAB + (size_t)m * Cdim + c0) = o;
        }
    } else {
        int idx = (bid - 8192) * 256 + threadIdx.x;  // [0, 4*C*C/8)
        int z   = idx >> 17;                         // C*C/8 == 131072
        int r   = idx & (Cdim * Cdim / 8 - 1);
        const float* src = (z == 0) ? Wk : (z == 1) ? Wv : (z == 2) ? Wr : Wo;
        const float4* sp = (const float4*)(src + (size_t)r * 8);
        float4 a = sp[0], b = sp[1];
        float v[8] = {a.x, a.y, a.z, a.w, b.x, b.y, b.z, b.w};
        bf16x8 o;
        #pragma unroll
        for (int j = 0; j < 8; ++j) o[j] = f2bs(v[j]);
        *(bf16x8*)(wbf + (size_t)z * Cdim * Cdim + (size_t)r * 8) = o;
    }
}

// ---------------------------------------------------------------------------
// gemm256: 256x256 tile, BK=64, 8 waves (2Mx4N), double-buffered LDS,
// XOR chunk^row&7 swizzle (T2), r8 2-phase K-loop.
// ROUND 12 mapping: z=0/z=1 blocks of the SAME (yt,nt) tile are ADJACENT in
// the per-XCD sequence (s<64: pair=s>>1, z=s&1; s>=64: z=2). The k/v pair is
// co-resident on one XCD, so their complementary interleaved half-sector
// stores merge in that XCD's L2 and evict as full sectors (fixes r9's RMW
// WRITE_SIZE 171 MB). FUSED: z<2 -> kv interleaved bf16 into o0
// (kv[(row*C+cc)*2+z]); z=2 -> sigmoid(r) bf16 into o2. Non-fused: f32 o0.
// ---------------------------------------------------------------------------
template<int FUSED>
__global__ __launch_bounds__(512, 2) void gemm256(
    const short* __restrict__ Abase,
    const short* __restrict__ Wbase,
    void* __restrict__ o0, void* __restrict__ o2)
{
    __shared__ __align__(16) char lds[131072];

    const int tid  = threadIdx.x;
    const int lane = tid & 63;
    const int wv   = tid >> 6;
    const int wm   = wv >> 2, wn = wv & 3;       // 2 x 4 waves
    const int NT   = Cdim / 64;                  // 16 K-tiles

    int orig = blockIdx.y * (FUSED ? 12 : 4) + blockIdx.x;
    int xcd  = orig & 7;
    int s    = orig >> 3;
    int z, nt, yt;
    if (FUSED) {
        if (s < 64) { int pr = s >> 1; z = s & 1; nt = pr & 3; yt = xcd * 8 + (pr >> 2); }
        else        { int rm = s - 64; z = 2;     nt = rm & 3; yt = xcd * 8 + (rm >> 2); }
    } else {
        z  = 0;
        nt = s & 3;
        yt = xcd * 8 + (s >> 2);
    }

    const short* A  = Abase + (size_t)z * SLAB;
    const short* Bm = Wbase + (size_t)z * Cdim * Cdim;
    const int m0 = yt * 256;
    const int n0 = nt * 256;

    f32x4 acc[8][4] = {};

    // per-lane read offsets (bytes)
    const int lm = lane & 15, lq = lane >> 4, lb7 = lane & 7;
    int ck[2];
    #pragma unroll
    for (int ks = 0; ks < 2; ++ks) ck[ks] = (((ks * 4 + lq) ^ lb7) << 4);
    int aoff[8];
    #pragma unroll
    for (int i = 0; i < 8; ++i) aoff[i] = (i * 16 + lm) * 128;
    int boff[4];
    #pragma unroll
    for (int j = 0; j < 4; ++j) boff[j] = ((wn & 1) * 64 + j * 16 + lm) * 128;
    const int aReg = wm << 14;                   // A-lo / A-hi
    const int bReg = 32768 + ((wn >> 1) << 14);  // B-lo / B-hi

    // stage one half-tile (2 x gload_lds, pre-swizzled global source)
    const int rlo  = tid >> 3;                   // 0..63
    const int clog = (tid & 7) ^ (rlo & 7);
    auto STAGE = [&](int tt, int part) {
        const short* mat = (part < 2) ? A : Bm;
        int rb = ((part < 2) ? m0 : n0) + ((part & 1) << 7);
        const short* g0 = mat + (size_t)(rb + rlo)      * Cdim + (tt << 6) + (clog << 3);
        const short* g1 = mat + (size_t)(rb + 64 + rlo) * Cdim + (tt << 6) + (clog << 3);
        char* l = lds + ((tt & 1) << 16) + (part << 14) + tid * 16;
        GLOAD_LDS16(g0, l);
        GLOAD_LDS16(g1, l + 8192);
    };

    // prologue: t0 all 4 halves + t1 A halves; t0 resident, t1.A in flight
    STAGE(0, 0); STAGE(0, 1); STAGE(0, 2); STAGE(0, 3);
    STAGE(1, 0); STAGE(1, 1);
    asm volatile("s_waitcnt vmcnt(4)" ::: "memory");
    SBAR();

    bf16x8 a0[4][2], a4[4][2], b01[2][2], b23[2][2];

    #pragma unroll 1
    for (int kt = 0; kt < NT; ++kt) {
        const char* base = lds + ((kt & 1) << 16);

        // ---- Ph1: all fragment reads; stage (kt+1).B; MFMA Q00 + Q10 ----
        #pragma unroll
        for (int i = 0; i < 4; ++i)
            #pragma unroll
            for (int ks = 0; ks < 2; ++ks)
                a0[i][ks] = *(const bf16x8*)(base + aReg + aoff[i] + ck[ks]);
        #pragma unroll
        for (int j = 0; j < 2; ++j)
            #pragma unroll
            for (int ks = 0; ks < 2; ++ks)
                b01[j][ks] = *(const bf16x8*)(base + bReg + boff[j] + ck[ks]);
        #pragma unroll
        for (int i = 0; i < 4; ++i)
            #pragma unroll
            for (int ks = 0; ks < 2; ++ks)
                a4[i][ks] = *(const bf16x8*)(base + aReg + aoff[i + 4] + ck[ks]);
        #pragma unroll
        for (int j = 0; j < 2; ++j)
            #pragma unroll
            for (int ks = 0; ks < 2; ++ks)
                b23[j][ks] = *(const bf16x8*)(base + bReg + boff[j + 2] + ck[ks]);
        if (kt + 1 < NT) { STAGE(kt + 1, 2); STAGE(kt + 1, 3); }
        __builtin_amdgcn_s_setprio(1);
        #pragma unroll
        for (int ks = 0; ks < 2; ++ks)
            #pragma unroll
            for (int i = 0; i < 4; ++i)
                #pragma unroll
                for (int j = 0; j < 2; ++j)
                    acc[i][j] = __builtin_amdgcn_mfma_f32_16x16x32_bf16(
                        a0[i][ks], b01[j][ks], acc[i][j], 0, 0, 0);
        #pragma unroll
        for (int ks = 0; ks < 2; ++ks)
            #pragma unroll
            for (int i = 0; i < 4; ++i)
                #pragma unroll
                for (int j = 0; j < 2; ++j)
                    acc[i + 4][j] = __builtin_amdgcn_mfma_f32_16x16x32_bf16(
                        a4[i][ks], b01[j][ks], acc[i + 4][j], 0, 0, 0);
        __builtin_amdgcn_s_setprio(0);
        SBAR();

        // ---- Ph2: stage (kt+2).A; MFMA Q11 + Q01 (held regs); vmcnt ----
        if (kt + 2 < NT) { STAGE(kt + 2, 0); STAGE(kt + 2, 1); }
        __builtin_amdgcn_s_setprio(1);
        #pragma unroll
        for (int ks = 0; ks < 2; ++ks)
            #pragma unroll
            for (int i = 0; i < 4; ++i)
                #pragma unroll
                for (int j = 0; j < 2; ++j)
                    acc[i + 4][j + 2] = __builtin_amdgcn_mfma_f32_16x16x32_bf16(
                        a4[i][ks], b23[j][ks], acc[i + 4][j + 2], 0, 0, 0);
        #pragma unroll
        for (int ks = 0; ks < 2; ++ks)
            #pragma unroll
            for (int i = 0; i < 4; ++i)
                #pragma unroll
                for (int j = 0; j < 2; ++j)
                    acc[i][j + 2] = __builtin_amdgcn_mfma_f32_16x16x32_bf16(
                        a0[i][ks], b23[j][ks], acc[i][j + 2], 0, 0, 0);
        __builtin_amdgcn_s_setprio(0);
        if      (kt + 2 < NT) { asm volatile("s_waitcnt vmcnt(4)" ::: "memory"); }
        else if (kt + 1 < NT) { asm volatile("s_waitcnt vmcnt(0)" ::: "memory"); }
        SBAR();
    }

    // epilogue: C/D layout col = lane&15, row = (lane>>4)*4 + r  [m89]
    int col0 = n0 + wn * 64 + lm;
    int row0 = m0 + wm * 128 + (lq << 2);
    #pragma unroll
    for (int i = 0; i < 8; ++i) {
        #pragma unroll
        for (int j = 0; j < 4; ++j) {
            #pragma unroll
            for (int r = 0; r < 4; ++r) {
                int row = row0 + i * 16 + r;
                int cc  = col0 + j * 16;
                float vvv = acc[i][j][r];
                if (FUSED) {
                    if (z == 2) {
                        ((short*)o2)[(size_t)row * Cdim + cc] =
                            f2bs(1.f / (1.f + __expf(-vvv)));
                    } else {
                        ((short*)o0)[((size_t)row * Cdim + cc) * 2 + z] = f2bs(vvv);
                    }
                } else {
                    ((float*)o0)[(size_t)row * Cdim + cc] = vvv;
                }
            }
        }
    }
}

// ---------------------------------------------------------------------------
// wkv_chunked (r9 structure): chunked-parallel stable WKV scan.
// k,v packed as one dword per (channel,t); r PRE-SIGMOIDED bf16.
// Block: CSUB=32 channels x NC=32 chunks = 1024 threads; grid = Bb*Cdim/32.
// ---------------------------------------------------------------------------
__global__ __launch_bounds__(1024) void wkv_chunked(
    const int* __restrict__ kv, const short* __restrict__ srb,
    const float* __restrict__ w, const float* __restrict__ u,
    short* __restrict__ rwkv)
{
    __shared__ float sp[NC][CSUB];
    __shared__ float sq[NC][CSUB];
    __shared__ float so[NC][CSUB];

    int tid = threadIdx.x;
    int cl  = tid & (CSUB - 1);
    int ch  = tid >> 5;                 // chunk index 0..NC-1
    int b   = blockIdx.x >> 5;          // grid = Bb * (Cdim/CSUB) = 8*32
    int cg  = blockIdx.x & 31;
    int c   = cg * CSUB + cl;

    float wexp = -__expf(w[c]);
    float uu   = u[c];
    size_t coff = (size_t)b * Tt * Cdim + (size_t)(ch * LCH) * Cdim + c;

    // ---- phase 1: local chunk summary from zero state ----
    float p = 0.f, q = 0.f, o = -1e30f;
    #pragma unroll 8
    for (int t = 0; t < LCH; ++t) {
        size_t off = coff + (size_t)t * Cdim;
        int pk = kv[off];
        float kt = bs2f((short)(pk & 0xffff));
        float vt = bs2f((short)((unsigned)pk >> 16));
        float wo  = wexp + o;
        float no  = fmaxf(wo, kt);
        float A   = __expf(wo - no);
        float B2  = __expf(kt - no);
        p = A * p + B2 * vt;
        q = A * q + B2;
        o = no;
    }
    sp[ch][cl] = p; sq[ch][cl] = q; so[ch][cl] = o;
    __syncthreads();

    // ---- phase 2: exclusive combine-scan over chunks (1 thread / channel) ----
    if (tid < CSUB) {
        float Ld = wexp * (float)LCH;   // decay of o over a full chunk
        float cp = 0.f, cq = 0.f, co = -1e30f;
        for (int j = 0; j < NC; ++j) {
            float lp = sp[j][tid], lq = sq[j][tid], lo = so[j][tid];
            sp[j][tid] = cp; sq[j][tid] = cq; so[j][tid] = co;  // incoming state
            float od = co + Ld;
            float no = fmaxf(od, lo);
            float A  = __expf(od - no);
            float B2 = __expf(lo - no);
            cp = A * cp + B2 * lp;
            cq = A * cq + B2 * lq;
            co = no;
        }
    }
    __syncthreads();

    // ---- phase 3: outputs from incoming state ----
    p = sp[ch][cl]; q = sq[ch][cl]; o = so[ch][cl];
    #pragma unroll 8
    for (int t = 0; t < LCH; ++t) {
        size_t off = coff + (size_t)t * Cdim;
        int pk = kv[off];
        float kt = bs2f((short)(pk & 0xffff));
        float vt = bs2f((short)((unsigned)pk >> 16));
        float sr = bs2f(srb[off]);       // sigmoid already applied in GEMM

        float uk  = uu + kt;
        float no  = fmaxf(o, uk);
        float Aa  = __expf(o - no);
        float Bc  = __expf(uk - no);
        float out = (Aa * p + Bc * vt) / (Aa * q + Bc);

        float wo  = wexp + o;
        float no2 = fmaxf(wo, kt);
        float A2  = __expf(wo - no2);
        float B2  = __expf(kt - no2);
        p = A2 * p + B2 * vt;
        q = A2 * q + B2;
        o = no2;

        rwkv[off] = f2bs(sr * out);
    }
}

// ---------------------------------------------------------------------------
extern "C" void kernel_launch(void* const* d_in, const int* in_sizes, int n_in,
                              void* d_out, int out_size, void* d_ws, size_t ws_size,
                              hipStream_t stream)
{
    const float* x    = (const float*)d_in[0];
    const float* w    = (const float*)d_in[1];
    const float* u    = (const float*)d_in[2];
    const float* mixk = (const float*)d_in[3];
    const float* mixv = (const float*)d_in[4];
    const float* mixr = (const float*)d_in[5];
    const float* Wk   = (const float*)d_in[6];
    const float* Wv   = (const float*)d_in[7];
    const float* Wr   = (const float*)d_in[8];
    const float* Wo   = (const float*)d_in[9];

    char* ws = (char*)d_ws;
    short* xmix = (short*)ws;                        // 3 slabs bf16 = 96 MiB
    short* wbf  = (short*)(ws + 3 * SLAB * 2);       // 4*C*C bf16 = 8 MiB
    short* rbuf = (short*)(ws + 3 * SLAB * 2 + (size_t)4 * Cdim * Cdim * 2); // 32 MiB
    short* rwkv = (short*)ws;                        // reuses dead xmix slab 0
    int*   kvbf = (int*)d_out;                       // k,v interleaved: 64 MiB

    // single prep dispatch: 8192 xmix blocks + 2048 W blocks
    prep_all<<<8192 + 2048, 256, 0, stream>>>(x, mixk, mixv, mixr,
                                              Wk, Wv, Wr, Wo, xmix, wbf);

    // fused k/v/r GEMM: grid (12,64) = 768 blocks; kv pair-adjacent mapping
    dim3 gf(12, BT / 256);
    gemm256<1><<<gf, 512, 0, stream>>>(xmix, wbf, kvbf, rbuf);

    wkv_chunked<<<Bb * (Cdim / CSUB), 1024, 0, stream>>>(kvbf, rbuf, w, u, rwkv);

    // output GEMM: grid (4,64) = 256 blocks, f32 out (overwrites dead kv)
    dim3 go(Cdim / 256, BT / 256);
    gemm256<0><<<go, 512, 0, stream>>>(rwkv, wbf + 3 * (size_t)Cdim * Cdim,
                                       (float*)d_out, nullptr);
}